// Round 8
// baseline (117.590 us; speedup 1.0000x reference)
//
#include <hip/hip_runtime.h>

#define DIM 4096
#define K_SEL 204            // int(4096 * (1.0 - 0.95)) == 204
#define CAP 256              // interval candidates: mean 165, sd 12.6 (7 sigma)
#define WPB 4                // waves per block (one row per wave per step, NO barriers)
#define NWAVES 4096          // 1024 blocks * 4 waves
#define RPW 4                // rows per wave (16384 / 4096)
#define LOF 1.4375f          // P(cnt(>LOF) < K)  ~ 6 sigma safe (fixed dataset, verified R2-R7)
#define HIF 1.8125f          // P(cnt(>HIF) >= K) ~ 5 sigma safe
#define KLO 0x3FB80000u      // bits of 1.4375
#define KHI 0x3FE80000u      // bits of 1.8125

typedef float nfloat4 __attribute__((ext_vector_type(4)));   // native vec for nt-store

// Monotonic key for the (never-taken) exact fallback: handles any floats.
__device__ __forceinline__ unsigned int fkey(float f) {
    unsigned int u = __float_as_uint(f);
    return (u & 0x80000000u) ? ~u : (u | 0x80000000u);
}
__device__ __forceinline__ float finv(unsigned int k) {
    unsigned int u = (k & 0x80000000u) ? (k ^ 0x80000000u) : ~k;
    return __uint_as_float(u);
}
// popcount of mask bits strictly below this lane (v_mbcnt_lo + v_mbcnt_hi)
__device__ __forceinline__ unsigned int prefcount(unsigned long long m) {
    return __builtin_amdgcn_mbcnt_hi((unsigned int)(m >> 32),
           __builtin_amdgcn_mbcnt_lo((unsigned int)m, 0u));
}
// nontemporal float4 store: keep the 256MB output stream OUT of L3 so the
// (exactly L3-sized) input stays Infinity-Cache-resident across graph replays.
// (R5 counters: FETCH dropped to ~half the input = L3 equilibrium. Keep.)
__device__ __forceinline__ void nt_store4(float4* p, float4 w) {
    nfloat4 nv;
    nv.x = w.x; nv.y = w.y; nv.z = w.z; nv.w = w.w;
    __builtin_nontemporal_store(nv, (nfloat4*)p);
}

// Exact top-K selection + masked write for one row held in registers v[16].
// Wave-private; zero barriers. wc = this wave's 256-entry LDS slice.
__device__ __forceinline__ void process_row(const float4 (&v)[16], float* wc,
                                            int lane, float4* ov) {
    // ---- fused count + compact of interval candidates (LOF, HIF] ----
    // positive-float trick: f in (LOF,HIF]  <=>  (bits(f)-KLO-1) < (KHI-KLO)
    // negatives/NaN have bits >= 0x8000..., failing the unsigned range test.
    unsigned int cU = 0, ccnt = 0;
    #pragma unroll
    for (int c = 0; c < 16; ++c) {
        float fv[4] = {v[c].x, v[c].y, v[c].z, v[c].w};
        #pragma unroll
        for (int j = 0; j < 4; ++j) {
            float f = fv[j];
            unsigned int u = __float_as_uint(f);
            bool inR = (u - (KLO + 1u)) < (KHI - KLO);   // candidate
            bool pU  = f > HIF;
            unsigned long long mC = __ballot(inR);
            unsigned long long mU = __ballot(pU);
            unsigned int pos = ccnt + prefcount(mC);
            if (inR && (pos < CAP)) wc[pos] = f;         // exec-masked store
            cU   += (unsigned)__popcll(mU);
            ccnt += (unsigned)__popcll(mC);
        }
    }

    const bool fast = (cU < K_SEL) && (cU + ccnt >= K_SEL) && (ccnt <= CAP);
    float thrf;
    unsigned int gt, eqc;

    if (fast) {
        // wave-private LDS readback (compiler inserts lgkmcnt; no barrier)
        float c0 = (lane       < (int)ccnt) ? wc[lane      ] : 0.0f;
        float c1 = (lane + 64  < (int)ccnt) ? wc[lane +  64] : 0.0f;
        float c2 = (lane + 128 < (int)ccnt) ? wc[lane + 128] : 0.0f;
        float c3 = (lane + 192 < (int)ccnt) ? wc[lane + 192] : 0.0f;
        // binary search on positive-float bit patterns in (KLO, KHI]
        unsigned int lo = KLO, hi = KHI;
        unsigned int c_lo = cU + ccnt, c_hi = cU;      // cnt_gt at both ends
        while (hi - lo > 1) {
            unsigned int mid = lo + ((hi - lo) >> 1);
            float midf = __uint_as_float(mid);
            unsigned int cm = cU
                + (unsigned)__popcll(__ballot(c0 > midf))
                + (unsigned)__popcll(__ballot(c1 > midf))
                + (unsigned)__popcll(__ballot(c2 > midf))
                + (unsigned)__popcll(__ballot(c3 > midf));
            if (cm >= K_SEL) { lo = mid; c_lo = cm; }
            else             { hi = mid; c_hi = cm; }
        }
        thrf = __uint_as_float(hi);    // k-th largest value
        gt = c_hi;                     // strictly greater
        eqc = c_lo - c_hi;             // equal (adjacent bit patterns -> exact)
    } else {
        // ---- exact fallback: 32-step search in monotonic-key domain ----
        unsigned int c_lo = 0;
        #pragma unroll
        for (int c = 0; c < 16; ++c) {
            c_lo += (unsigned)__popcll(__ballot(fkey(v[c].x) > 0u));
            c_lo += (unsigned)__popcll(__ballot(fkey(v[c].y) > 0u));
            c_lo += (unsigned)__popcll(__ballot(fkey(v[c].z) > 0u));
            c_lo += (unsigned)__popcll(__ballot(fkey(v[c].w) > 0u));
        }
        unsigned int lo = 0u, hi = 0xFFFFFFFFu, c_hi = 0;
        while (hi - lo > 1) {
            unsigned int mid = lo + ((hi - lo) >> 1);
            unsigned int cm = 0;
            #pragma unroll
            for (int c = 0; c < 16; ++c) {
                cm += (unsigned)__popcll(__ballot(fkey(v[c].x) > mid));
                cm += (unsigned)__popcll(__ballot(fkey(v[c].y) > mid));
                cm += (unsigned)__popcll(__ballot(fkey(v[c].z) > mid));
                cm += (unsigned)__popcll(__ballot(fkey(v[c].w) > mid));
            }
            if (cm >= K_SEL) { lo = mid; c_lo = cm; }
            else             { hi = mid; c_hi = cm; }
        }
        thrf = finv(hi);
        gt = c_hi;
        eqc = c_lo - c_hi;
    }

    const unsigned int need = K_SEL - gt;     // >= 1 by search invariant

    if (eqc == need) {
        // common case: keep everything >= thr (exactly K survive)
        #pragma unroll
        for (int c = 0; c < 16; ++c) {
            float4 w = v[c];
            w.x = (w.x >= thrf) ? w.x : 0.0f;
            w.y = (w.y >= thrf) ? w.y : 0.0f;
            w.z = (w.z >= thrf) ? w.z : 0.0f;
            w.w = (w.w >= thrf) ? w.w : 0.0f;
            nt_store4(&ov[lane + 64 * c], w);
        }
    } else {
        // rare tie path: keep first `need` equals in global index order
        // element index = 256*c + 4*lane + j  -> order (c, lane, j)
        unsigned int base_c = 0;
        #pragma unroll
        for (int c = 0; c < 16; ++c) {
            unsigned long long m0 = __ballot(v[c].x == thrf);
            unsigned long long m1 = __ballot(v[c].y == thrf);
            unsigned long long m2 = __ballot(v[c].z == thrf);
            unsigned long long m3 = __ballot(v[c].w == thrf);
            unsigned int pl = prefcount(m0) + prefcount(m1)
                            + prefcount(m2) + prefcount(m3);
            unsigned int b0 = (unsigned)((m0 >> lane) & 1ull);
            unsigned int b1 = (unsigned)((m1 >> lane) & 1ull);
            unsigned int b2 = (unsigned)((m2 >> lane) & 1ull);
            unsigned int r0 = base_c + pl;
            unsigned int r1 = r0 + b0;
            unsigned int r2 = r1 + b1;
            unsigned int r3 = r2 + b2;
            float4 w = v[c];
            w.x = (w.x > thrf || (w.x == thrf && r0 < need)) ? w.x : 0.0f;
            w.y = (w.y > thrf || (w.y == thrf && r1 < need)) ? w.y : 0.0f;
            w.z = (w.z > thrf || (w.z == thrf && r2 < need)) ? w.z : 0.0f;
            w.w = (w.w > thrf || (w.w == thrf && r3 < need)) ? w.w : 0.0f;
            nt_store4(&ov[lane + 64 * c], w);
            base_c += (unsigned)__popcll(m0) + (unsigned)__popcll(m1)
                    + (unsigned)__popcll(m2) + (unsigned)__popcll(m3);
        }
    }
}

#define LOAD16(dst, row) do {                                            \
        const float4* _p = (const float4*)(x + (size_t)(row) * DIM);     \
        _Pragma("unroll")                                                \
        for (int _c = 0; _c < 16; ++_c) dst[_c] = _p[lane + 64 * _c];    \
    } while (0)

// 4 waves/block, each wave owns RPW=4 rows, double-buffered A/B so the next
// row's 16 loads are in flight while the current row computes. Zero barriers.
// launch_bounds(256,3): ~170-VGPR cap -- fits 2x64 data regs + working set
// WITHOUT spilling (R6: a too-tight cap -> scratch -> 2x regression).
__global__ __launch_bounds__(256, 3) void sparsify_topk(
        const float* __restrict__ x, float* __restrict__ out) {
    __shared__ float wc_all[WPB][CAP];        // 4 KB, partitioned per wave

    const int wave = threadIdx.x >> 6;
    const int lane = threadIdx.x & 63;
    float* wc = wc_all[wave];
    const int gw = blockIdx.x * WPB + wave;   // global wave id, 0..4095
    // rows: gw + i*NWAVES, i = 0..3 (concurrent rows contiguous across waves)

    float4 A[16], B[16];                      // named buffers: static reg indexing

    LOAD16(A, gw);                                        // row 0 -> A
    LOAD16(B, gw + NWAVES);                               // prefetch row 1 -> B
    process_row(A, wc, lane, (float4*)(out + (size_t)gw * DIM));

    LOAD16(A, gw + 2 * NWAVES);                           // prefetch row 2 -> A
    process_row(B, wc, lane, (float4*)(out + (size_t)(gw + NWAVES) * DIM));

    LOAD16(B, gw + 3 * NWAVES);                           // prefetch row 3 -> B
    process_row(A, wc, lane, (float4*)(out + (size_t)(gw + 2 * NWAVES) * DIM));

    process_row(B, wc, lane, (float4*)(out + (size_t)(gw + 3 * NWAVES) * DIM));
}

extern "C" void kernel_launch(void* const* d_in, const int* in_sizes, int n_in,
                              void* d_out, int out_size, void* d_ws, size_t ws_size,
                              hipStream_t stream) {
    const float* x = (const float*)d_in[0];
    float* out = (float*)d_out;
    (void)in_sizes; (void)n_in; (void)d_ws; (void)ws_size; (void)out_size;
    sparsify_topk<<<NWAVES / WPB, 256, 0, stream>>>(x, out);   // 1024 blocks
}

// Round 9
// 108.581 us; speedup vs baseline: 1.0830x; 1.0830x over previous
//
#include <hip/hip_runtime.h>

#define DIM 4096
#define K_SEL 204            // int(4096 * (1.0 - 0.95)) == 204
#define CAP 256              // interval candidates: mean 165, sd 12.6 (7 sigma)
#define WPB 4                // 4 independent rows per block (one per wave, NO barriers)
#define LOF 1.4375f          // P(cnt(>LOF) < K)  ~ 6 sigma safe (fixed dataset, verified R2-R8)
#define HIF 1.8125f          // P(cnt(>HIF) >= K) ~ 5 sigma safe
#define KLO 0x3FB80000u      // bits of 1.4375
#define KHI 0x3FE80000u      // bits of 1.8125

typedef float nfloat4 __attribute__((ext_vector_type(4)));   // native vec for nt-store

// Monotonic key for the (never-taken) exact fallback: handles any floats.
__device__ __forceinline__ unsigned int fkey(float f) {
    unsigned int u = __float_as_uint(f);
    return (u & 0x80000000u) ? ~u : (u | 0x80000000u);
}
__device__ __forceinline__ float finv(unsigned int k) {
    unsigned int u = (k & 0x80000000u) ? (k ^ 0x80000000u) : ~k;
    return __uint_as_float(u);
}
// popcount of mask bits strictly below this lane (v_mbcnt_lo + v_mbcnt_hi)
__device__ __forceinline__ unsigned int prefcount(unsigned long long m) {
    return __builtin_amdgcn_mbcnt_hi((unsigned int)(m >> 32),
           __builtin_amdgcn_mbcnt_lo((unsigned int)m, 0u));
}
// nontemporal float4 store: keep the 256MB output stream OUT of L3 so the
// (exactly L3-sized) input stays Infinity-Cache-resident across graph replays.
// (R5 counters: FETCH dropped to ~half the input = L3 equilibrium. Keep.)
__device__ __forceinline__ void nt_store4(float4* p, float4 w) {
    nfloat4 nv;
    nv.x = w.x; nv.y = w.y; nv.z = w.z; nv.w = w.w;
    __builtin_nontemporal_store(nv, (nfloat4*)p);
}

// 256 threads = 4 waves, each wave owns one ROW. Zero __syncthreads.
// launch_bounds(256,4): 128-VGPR cap (R6: tighter cap -> spills -> 2x regression;
// R8: double-buffer needed >128 -> rematerialization -> regression. 1 row/wave fits.)
__global__ __launch_bounds__(256, 4) void sparsify_topk(
        const float* __restrict__ x, float* __restrict__ out) {
    __shared__ float wc_all[WPB][CAP];        // 4 KB, partitioned per wave

    const int wave = threadIdx.x >> 6;
    const int lane = threadIdx.x & 63;
    float* wc = wc_all[wave];
    const size_t base = (size_t)(blockIdx.x * WPB + wave) * DIM;

    // ---- load row: 16 x float4 per lane, 64 VGPRs, coalesced 1KB/instr ----
    const float4* xv = (const float4*)(x + base);
    float4 v[16];
    #pragma unroll
    for (int c = 0; c < 16; ++c) v[c] = xv[lane + 64 * c];

    // ---- pass 1: per-lane candidate/upper counts (pure VALU, no cross-lane) ----
    // positive-float trick: f in (LOF,HIF]  <=>  (bits(f)-KLO-1) < (KHI-KLO);
    // negatives/NaN have bits >= 0x8000..., failing the unsigned range test.
    unsigned int lcnt = 0, lcU = 0;
    #pragma unroll
    for (int c = 0; c < 16; ++c) {
        float fv[4] = {v[c].x, v[c].y, v[c].z, v[c].w};
        #pragma unroll
        for (int j = 0; j < 4; ++j) {
            unsigned int u = __float_as_uint(fv[j]);
            lcnt += ((u - (KLO + 1u)) < (KHI - KLO)) ? 1u : 0u;
            lcU  += (fv[j] > HIF) ? 1u : 0u;
        }
    }
    // wave inclusive scan of lcnt (6 shfl_up) -> per-lane LDS write offsets
    unsigned int incl = lcnt;
    #pragma unroll
    for (int d = 1; d < 64; d <<= 1) {
        unsigned int n = __shfl_up(incl, d, 64);
        if (lane >= d) incl += n;
    }
    const unsigned int ccnt = __shfl(incl, 63, 64);   // wave total candidates
    unsigned int pos = incl - lcnt;                    // exclusive prefix
    // wave sum of lcU (6-step butterfly -> all lanes hold total)
    unsigned int cU = lcU;
    #pragma unroll
    for (int d = 1; d < 64; d <<= 1) cU += __shfl_xor(cU, d, 64);

    // ---- pass 2: each lane writes ITS candidates (predicated, no wave deps) ----
    #pragma unroll
    for (int c = 0; c < 16; ++c) {
        float fv[4] = {v[c].x, v[c].y, v[c].z, v[c].w};
        #pragma unroll
        for (int j = 0; j < 4; ++j) {
            unsigned int u = __float_as_uint(fv[j]);
            bool inR = (u - (KLO + 1u)) < (KHI - KLO);
            if (inR && pos < CAP) wc[pos] = fv[j];
            pos += inR ? 1u : 0u;
        }
    }

    const bool fast = (cU < K_SEL) && (cU + ccnt >= K_SEL) && (ccnt <= CAP);
    float thrf;
    unsigned int gt, eqc;

    if (fast) {
        // wave-private LDS readback (compiler inserts lgkmcnt; no barrier)
        float c0 = (lane       < (int)ccnt) ? wc[lane      ] : 0.0f;
        float c1 = (lane + 64  < (int)ccnt) ? wc[lane +  64] : 0.0f;
        float c2 = (lane + 128 < (int)ccnt) ? wc[lane + 128] : 0.0f;
        float c3 = (lane + 192 < (int)ccnt) ? wc[lane + 192] : 0.0f;
        // binary search on positive-float bit patterns in (KLO, KHI]
        unsigned int lo = KLO, hi = KHI;
        unsigned int c_lo = cU + ccnt, c_hi = cU;      // cnt_gt at both ends
        while (hi - lo > 1) {
            unsigned int mid = lo + ((hi - lo) >> 1);
            float midf = __uint_as_float(mid);
            unsigned int cm = cU
                + (unsigned)__popcll(__ballot(c0 > midf))
                + (unsigned)__popcll(__ballot(c1 > midf))
                + (unsigned)__popcll(__ballot(c2 > midf))
                + (unsigned)__popcll(__ballot(c3 > midf));
            if (cm >= K_SEL) { lo = mid; c_lo = cm; }
            else             { hi = mid; c_hi = cm; }
        }
        thrf = __uint_as_float(hi);    // k-th largest value
        gt = c_hi;                     // strictly greater
        eqc = c_lo - c_hi;             // equal (adjacent bit patterns -> exact)
    } else {
        // ---- exact fallback: 32-step search in monotonic-key domain ----
        unsigned int c_lo = 0;
        #pragma unroll
        for (int c = 0; c < 16; ++c) {
            c_lo += (unsigned)__popcll(__ballot(fkey(v[c].x) > 0u));
            c_lo += (unsigned)__popcll(__ballot(fkey(v[c].y) > 0u));
            c_lo += (unsigned)__popcll(__ballot(fkey(v[c].z) > 0u));
            c_lo += (unsigned)__popcll(__ballot(fkey(v[c].w) > 0u));
        }
        unsigned int lo = 0u, hi = 0xFFFFFFFFu, c_hi = 0;
        while (hi - lo > 1) {
            unsigned int mid = lo + ((hi - lo) >> 1);
            unsigned int cm = 0;
            #pragma unroll
            for (int c = 0; c < 16; ++c) {
                cm += (unsigned)__popcll(__ballot(fkey(v[c].x) > mid));
                cm += (unsigned)__popcll(__ballot(fkey(v[c].y) > mid));
                cm += (unsigned)__popcll(__ballot(fkey(v[c].z) > mid));
                cm += (unsigned)__popcll(__ballot(fkey(v[c].w) > mid));
            }
            if (cm >= K_SEL) { lo = mid; c_lo = cm; }
            else             { hi = mid; c_hi = cm; }
        }
        thrf = finv(hi);
        gt = c_hi;
        eqc = c_lo - c_hi;
    }

    const unsigned int need = K_SEL - gt;     // >= 1 by search invariant
    float4* ov = (float4*)(out + base);

    if (eqc == need) {
        // common case: keep everything >= thr (exactly K survive)
        #pragma unroll
        for (int c = 0; c < 16; ++c) {
            float4 w = v[c];
            w.x = (w.x >= thrf) ? w.x : 0.0f;
            w.y = (w.y >= thrf) ? w.y : 0.0f;
            w.z = (w.z >= thrf) ? w.z : 0.0f;
            w.w = (w.w >= thrf) ? w.w : 0.0f;
            nt_store4(&ov[lane + 64 * c], w);
        }
    } else {
        // rare tie path: keep first `need` equals in global index order
        // element index = 256*c + 4*lane + j  -> order (c, lane, j)
        unsigned int base_c = 0;
        #pragma unroll
        for (int c = 0; c < 16; ++c) {
            unsigned long long m0 = __ballot(v[c].x == thrf);
            unsigned long long m1 = __ballot(v[c].y == thrf);
            unsigned long long m2 = __ballot(v[c].z == thrf);
            unsigned long long m3 = __ballot(v[c].w == thrf);
            unsigned int pl = prefcount(m0) + prefcount(m1)
                            + prefcount(m2) + prefcount(m3);
            unsigned int b0 = (unsigned)((m0 >> lane) & 1ull);
            unsigned int b1 = (unsigned)((m1 >> lane) & 1ull);
            unsigned int b2 = (unsigned)((m2 >> lane) & 1ull);
            unsigned int r0 = base_c + pl;
            unsigned int r1 = r0 + b0;
            unsigned int r2 = r1 + b1;
            unsigned int r3 = r2 + b2;
            float4 w = v[c];
            w.x = (w.x > thrf || (w.x == thrf && r0 < need)) ? w.x : 0.0f;
            w.y = (w.y > thrf || (w.y == thrf && r1 < need)) ? w.y : 0.0f;
            w.z = (w.z > thrf || (w.z == thrf && r2 < need)) ? w.z : 0.0f;
            w.w = (w.w > thrf || (w.w == thrf && r3 < need)) ? w.w : 0.0f;
            nt_store4(&ov[lane + 64 * c], w);
            base_c += (unsigned)__popcll(m0) + (unsigned)__popcll(m1)
                    + (unsigned)__popcll(m2) + (unsigned)__popcll(m3);
        }
    }
}

extern "C" void kernel_launch(void* const* d_in, const int* in_sizes, int n_in,
                              void* d_out, int out_size, void* d_ws, size_t ws_size,
                              hipStream_t stream) {
    const float* x = (const float*)d_in[0];
    float* out = (float*)d_out;
    int rows = in_sizes[0] / DIM;             // 16384
    sparsify_topk<<<rows / WPB, 256, 0, stream>>>(x, out);
}

// Round 10
// 89.421 us; speedup vs baseline: 1.3150x; 1.2143x over previous
//
#include <hip/hip_runtime.h>

#define DIM 4096
#define K_SEL 204            // int(4096 * (1.0 - 0.95)) == 204
#define CAP 256              // interval candidates: mean 165, sd 12.6 (7 sigma)
#define WPB 4                // 4 independent rows per block (one per wave, NO barriers)
#define LOF 1.4375f          // P(cnt(>LOF) < K)  ~ 6 sigma safe (fixed dataset, verified R2-R9)
#define HIF 1.8125f          // P(cnt(>HIF) >= K) ~ 5 sigma safe
#define KLO 0x3FB80000u      // bits of 1.4375
#define KHI 0x3FE80000u      // bits of 1.8125

typedef float nfloat4 __attribute__((ext_vector_type(4)));   // native vec for nt ops

// Monotonic key for the (never-taken) exact fallback: handles any floats.
__device__ __forceinline__ unsigned int fkey(float f) {
    unsigned int u = __float_as_uint(f);
    return (u & 0x80000000u) ? ~u : (u | 0x80000000u);
}
__device__ __forceinline__ float finv(unsigned int k) {
    unsigned int u = (k & 0x80000000u) ? (k ^ 0x80000000u) : ~k;
    return __uint_as_float(u);
}
// popcount of mask bits strictly below this lane (v_mbcnt_lo + v_mbcnt_hi)
__device__ __forceinline__ unsigned int prefcount(unsigned long long m) {
    return __builtin_amdgcn_mbcnt_hi((unsigned int)(m >> 32),
           __builtin_amdgcn_mbcnt_lo((unsigned int)m, 0u));
}
// nontemporal store: keep the 256MB output stream OUT of L3 (R5: halved FETCH).
__device__ __forceinline__ void nt_store4(float4* p, float4 w) {
    nfloat4 nv;
    nv.x = w.x; nv.y = w.y; nv.z = w.z; nv.w = w.w;
    __builtin_nontemporal_store(nv, (nfloat4*)p);
}
// nontemporal load: stream this chunk from HBM without allocating in L3.
__device__ __forceinline__ float4 nt_load4(const float4* p) {
    nfloat4 nv = __builtin_nontemporal_load((const nfloat4*)p);
    float4 w; w.x = nv.x; w.y = nv.y; w.z = nv.z; w.w = nv.w;
    return w;
}

// 256 threads = 4 waves, each wave owns one ROW. Zero __syncthreads.
// launch_bounds(256,4): 128-VGPR cap. (R6: tighter cap -> spills -> 2x regression;
// R8/R9: restructures that pushed live state past 64 VGPRs -> scratch -> regression.
// This is R7's proven 82us structure; only the load cache policy changes.)
__global__ __launch_bounds__(256, 4) void sparsify_topk(
        const float* __restrict__ x, float* __restrict__ out) {
    __shared__ float wc_all[WPB][CAP];        // 4 KB, partitioned per wave

    const int wave = threadIdx.x >> 6;
    const int lane = threadIdx.x & 63;
    float* wc = wc_all[wave];
    const size_t base = (size_t)(blockIdx.x * WPB + wave) * DIM;

    // ---- load row: 16 x float4 per lane, coalesced 1KB/instr ----
    // Static cache partition: chunks c%4==0 (25% = 64MB of input) load
    // NONTEMPORAL (stream from HBM, no L3 allocate); the other 75% (192MB)
    // then FITS the 256MB Infinity Cache and stays resident across graph
    // replays, instead of the 50% thrash equilibrium measured in R5-R7.
    const float4* xv = (const float4*)(x + base);
    float4 v[16];
    #pragma unroll
    for (int c = 0; c < 16; ++c) {
        if ((c & 3) == 0) v[c] = nt_load4(xv + lane + 64 * c);
        else              v[c] = xv[lane + 64 * c];
    }

    // ---- fused count + compact of interval candidates (LOF, HIF] ----
    // positive-float trick: f in (LOF,HIF]  <=>  (bits(f)-KLO-1) < (KHI-KLO)
    // negatives/NaN have bits >= 0x8000..., failing the unsigned range test.
    unsigned int cU = 0, ccnt = 0;
    #pragma unroll
    for (int c = 0; c < 16; ++c) {
        float fv[4] = {v[c].x, v[c].y, v[c].z, v[c].w};
        #pragma unroll
        for (int j = 0; j < 4; ++j) {
            float f = fv[j];
            unsigned int u = __float_as_uint(f);
            bool inR = (u - (KLO + 1u)) < (KHI - KLO);   // candidate
            bool pU  = f > HIF;
            unsigned long long mC = __ballot(inR);
            unsigned long long mU = __ballot(pU);
            unsigned int pos = ccnt + prefcount(mC);
            if (inR && (pos < CAP)) wc[pos] = f;         // exec-masked store
            cU   += (unsigned)__popcll(mU);
            ccnt += (unsigned)__popcll(mC);
        }
    }

    const bool fast = (cU < K_SEL) && (cU + ccnt >= K_SEL) && (ccnt <= CAP);
    float thrf;
    unsigned int gt, eqc;

    if (fast) {
        // wave-private LDS readback (compiler inserts lgkmcnt; no barrier)
        float c0 = (lane       < (int)ccnt) ? wc[lane      ] : 0.0f;
        float c1 = (lane + 64  < (int)ccnt) ? wc[lane +  64] : 0.0f;
        float c2 = (lane + 128 < (int)ccnt) ? wc[lane + 128] : 0.0f;
        float c3 = (lane + 192 < (int)ccnt) ? wc[lane + 192] : 0.0f;
        // binary search on positive-float bit patterns in (KLO, KHI]
        unsigned int lo = KLO, hi = KHI;
        unsigned int c_lo = cU + ccnt, c_hi = cU;      // cnt_gt at both ends
        while (hi - lo > 1) {
            unsigned int mid = lo + ((hi - lo) >> 1);
            float midf = __uint_as_float(mid);
            unsigned int cm = cU
                + (unsigned)__popcll(__ballot(c0 > midf))
                + (unsigned)__popcll(__ballot(c1 > midf))
                + (unsigned)__popcll(__ballot(c2 > midf))
                + (unsigned)__popcll(__ballot(c3 > midf));
            if (cm >= K_SEL) { lo = mid; c_lo = cm; }
            else             { hi = mid; c_hi = cm; }
        }
        thrf = __uint_as_float(hi);    // k-th largest value
        gt = c_hi;                     // strictly greater
        eqc = c_lo - c_hi;             // equal (adjacent bit patterns -> exact)
    } else {
        // ---- exact fallback: 32-step search in monotonic-key domain ----
        unsigned int c_lo = 0;
        #pragma unroll
        for (int c = 0; c < 16; ++c) {
            c_lo += (unsigned)__popcll(__ballot(fkey(v[c].x) > 0u));
            c_lo += (unsigned)__popcll(__ballot(fkey(v[c].y) > 0u));
            c_lo += (unsigned)__popcll(__ballot(fkey(v[c].z) > 0u));
            c_lo += (unsigned)__popcll(__ballot(fkey(v[c].w) > 0u));
        }
        unsigned int lo = 0u, hi = 0xFFFFFFFFu, c_hi = 0;
        while (hi - lo > 1) {
            unsigned int mid = lo + ((hi - lo) >> 1);
            unsigned int cm = 0;
            #pragma unroll
            for (int c = 0; c < 16; ++c) {
                cm += (unsigned)__popcll(__ballot(fkey(v[c].x) > mid));
                cm += (unsigned)__popcll(__ballot(fkey(v[c].y) > mid));
                cm += (unsigned)__popcll(__ballot(fkey(v[c].z) > mid));
                cm += (unsigned)__popcll(__ballot(fkey(v[c].w) > mid));
            }
            if (cm >= K_SEL) { lo = mid; c_lo = cm; }
            else             { hi = mid; c_hi = cm; }
        }
        thrf = finv(hi);
        gt = c_hi;
        eqc = c_lo - c_hi;
    }

    const unsigned int need = K_SEL - gt;     // >= 1 by search invariant
    float4* ov = (float4*)(out + base);

    if (eqc == need) {
        // common case: keep everything >= thr (exactly K survive)
        #pragma unroll
        for (int c = 0; c < 16; ++c) {
            float4 w = v[c];
            w.x = (w.x >= thrf) ? w.x : 0.0f;
            w.y = (w.y >= thrf) ? w.y : 0.0f;
            w.z = (w.z >= thrf) ? w.z : 0.0f;
            w.w = (w.w >= thrf) ? w.w : 0.0f;
            nt_store4(&ov[lane + 64 * c], w);
        }
    } else {
        // rare tie path: keep first `need` equals in global index order
        // element index = 256*c + 4*lane + j  -> order (c, lane, j)
        unsigned int base_c = 0;
        #pragma unroll
        for (int c = 0; c < 16; ++c) {
            unsigned long long m0 = __ballot(v[c].x == thrf);
            unsigned long long m1 = __ballot(v[c].y == thrf);
            unsigned long long m2 = __ballot(v[c].z == thrf);
            unsigned long long m3 = __ballot(v[c].w == thrf);
            unsigned int pl = prefcount(m0) + prefcount(m1)
                            + prefcount(m2) + prefcount(m3);
            unsigned int b0 = (unsigned)((m0 >> lane) & 1ull);
            unsigned int b1 = (unsigned)((m1 >> lane) & 1ull);
            unsigned int b2 = (unsigned)((m2 >> lane) & 1ull);
            unsigned int r0 = base_c + pl;
            unsigned int r1 = r0 + b0;
            unsigned int r2 = r1 + b1;
            unsigned int r3 = r2 + b2;
            float4 w = v[c];
            w.x = (w.x > thrf || (w.x == thrf && r0 < need)) ? w.x : 0.0f;
            w.y = (w.y > thrf || (w.y == thrf && r1 < need)) ? w.y : 0.0f;
            w.z = (w.z > thrf || (w.z == thrf && r2 < need)) ? w.z : 0.0f;
            w.w = (w.w > thrf || (w.w == thrf && r3 < need)) ? w.w : 0.0f;
            nt_store4(&ov[lane + 64 * c], w);
            base_c += (unsigned)__popcll(m0) + (unsigned)__popcll(m1)
                    + (unsigned)__popcll(m2) + (unsigned)__popcll(m3);
        }
    }
}

extern "C" void kernel_launch(void* const* d_in, const int* in_sizes, int n_in,
                              void* d_out, int out_size, void* d_ws, size_t ws_size,
                              hipStream_t stream) {
    const float* x = (const float*)d_in[0];
    float* out = (float*)d_out;
    int rows = in_sizes[0] / DIM;             // 16384
    sparsify_topk<<<rows / WPB, 256, 0, stream>>>(x, out);
}

// Round 11
// 82.473 us; speedup vs baseline: 1.4258x; 1.0842x over previous
//
#include <hip/hip_runtime.h>

#define DIM 4096
#define K_SEL 204            // int(4096 * (1.0 - 0.95)) == 204
#define CAP 256              // interval candidates: mean 165, sd 12.6 (7 sigma)
#define WPB 4                // 4 independent rows per block (one per wave, NO barriers)
#define LOF 1.4375f          // P(cnt(>LOF) < K)  ~ 6 sigma safe (fixed dataset, verified R2-R10)
#define HIF 1.8125f          // P(cnt(>HIF) >= K) ~ 5 sigma safe
#define KLO 0x3FB80000u      // bits of 1.4375
#define KHI 0x3FE80000u      // bits of 1.8125

typedef float nfloat4 __attribute__((ext_vector_type(4)));   // native vec for nt-store

// Monotonic key for the (never-taken) exact fallback: handles any floats.
__device__ __forceinline__ unsigned int fkey(float f) {
    unsigned int u = __float_as_uint(f);
    return (u & 0x80000000u) ? ~u : (u | 0x80000000u);
}
__device__ __forceinline__ float finv(unsigned int k) {
    unsigned int u = (k & 0x80000000u) ? (k ^ 0x80000000u) : ~k;
    return __uint_as_float(u);
}
// popcount of mask bits strictly below this lane (v_mbcnt_lo + v_mbcnt_hi)
__device__ __forceinline__ unsigned int prefcount(unsigned long long m) {
    return __builtin_amdgcn_mbcnt_hi((unsigned int)(m >> 32),
           __builtin_amdgcn_mbcnt_lo((unsigned int)m, 0u));
}
// nontemporal store: keep the 256MB output stream OUT of L3 so the
// (exactly L3-sized) input reaches its ~50% residency equilibrium across
// graph replays (R5: FETCH 262->131 GB-KB, -25us). nt-LOADS do nothing
// (R10: FETCH unchanged) -- L3 replacement is not source-controllable.
__device__ __forceinline__ void nt_store4(float4* p, float4 w) {
    nfloat4 nv;
    nv.x = w.x; nv.y = w.y; nv.z = w.z; nv.w = w.w;
    __builtin_nontemporal_store(nv, (nfloat4*)p);
}

// 256 threads = 4 waves, each wave owns one ROW. Zero __syncthreads.
// launch_bounds(256,4): 128-VGPR cap. Ledger: R6 (256,8) -> spills -> 2x
// regression; R8 dbuf needs >128 VGPR -> rematerialize -> regression; R9
// scan-restructure -> spills+conflicts -> regression; R10 nt-loads -> no-op.
// This R7 structure (82.4us) is the measured optimum: 6.5 TB/s logical
// (536MB/82.4us), above the 6.29 TB/s HBM copy ceiling via L3 read hits.
__global__ __launch_bounds__(256, 4) void sparsify_topk(
        const float* __restrict__ x, float* __restrict__ out) {
    __shared__ float wc_all[WPB][CAP];        // 4 KB, partitioned per wave

    const int wave = threadIdx.x >> 6;
    const int lane = threadIdx.x & 63;
    float* wc = wc_all[wave];
    const size_t base = (size_t)(blockIdx.x * WPB + wave) * DIM;

    // ---- load row: 16 x float4 per lane, 64 VGPRs, coalesced 1KB/instr ----
    const float4* xv = (const float4*)(x + base);
    float4 v[16];
    #pragma unroll
    for (int c = 0; c < 16; ++c) v[c] = xv[lane + 64 * c];

    // ---- fused count + compact of interval candidates (LOF, HIF] ----
    // positive-float trick: f in (LOF,HIF]  <=>  (bits(f)-KLO-1) < (KHI-KLO)
    // negatives/NaN have bits >= 0x8000..., failing the unsigned range test.
    unsigned int cU = 0, ccnt = 0;
    #pragma unroll
    for (int c = 0; c < 16; ++c) {
        float fv[4] = {v[c].x, v[c].y, v[c].z, v[c].w};
        #pragma unroll
        for (int j = 0; j < 4; ++j) {
            float f = fv[j];
            unsigned int u = __float_as_uint(f);
            bool inR = (u - (KLO + 1u)) < (KHI - KLO);   // candidate
            bool pU  = f > HIF;
            unsigned long long mC = __ballot(inR);
            unsigned long long mU = __ballot(pU);
            unsigned int pos = ccnt + prefcount(mC);
            if (inR && (pos < CAP)) wc[pos] = f;         // exec-masked store
            cU   += (unsigned)__popcll(mU);
            ccnt += (unsigned)__popcll(mC);
        }
    }

    const bool fast = (cU < K_SEL) && (cU + ccnt >= K_SEL) && (ccnt <= CAP);
    float thrf;
    unsigned int gt, eqc;

    if (fast) {
        // wave-private LDS readback (compiler inserts lgkmcnt; no barrier)
        float c0 = (lane       < (int)ccnt) ? wc[lane      ] : 0.0f;
        float c1 = (lane + 64  < (int)ccnt) ? wc[lane +  64] : 0.0f;
        float c2 = (lane + 128 < (int)ccnt) ? wc[lane + 128] : 0.0f;
        float c3 = (lane + 192 < (int)ccnt) ? wc[lane + 192] : 0.0f;
        // binary search on positive-float bit patterns in (KLO, KHI]
        unsigned int lo = KLO, hi = KHI;
        unsigned int c_lo = cU + ccnt, c_hi = cU;      // cnt_gt at both ends
        while (hi - lo > 1) {
            unsigned int mid = lo + ((hi - lo) >> 1);
            float midf = __uint_as_float(mid);
            unsigned int cm = cU
                + (unsigned)__popcll(__ballot(c0 > midf))
                + (unsigned)__popcll(__ballot(c1 > midf))
                + (unsigned)__popcll(__ballot(c2 > midf))
                + (unsigned)__popcll(__ballot(c3 > midf));
            if (cm >= K_SEL) { lo = mid; c_lo = cm; }
            else             { hi = mid; c_hi = cm; }
        }
        thrf = __uint_as_float(hi);    // k-th largest value
        gt = c_hi;                     // strictly greater
        eqc = c_lo - c_hi;             // equal (adjacent bit patterns -> exact)
    } else {
        // ---- exact fallback: 32-step search in monotonic-key domain ----
        unsigned int c_lo = 0;
        #pragma unroll
        for (int c = 0; c < 16; ++c) {
            c_lo += (unsigned)__popcll(__ballot(fkey(v[c].x) > 0u));
            c_lo += (unsigned)__popcll(__ballot(fkey(v[c].y) > 0u));
            c_lo += (unsigned)__popcll(__ballot(fkey(v[c].z) > 0u));
            c_lo += (unsigned)__popcll(__ballot(fkey(v[c].w) > 0u));
        }
        unsigned int lo = 0u, hi = 0xFFFFFFFFu, c_hi = 0;
        while (hi - lo > 1) {
            unsigned int mid = lo + ((hi - lo) >> 1);
            unsigned int cm = 0;
            #pragma unroll
            for (int c = 0; c < 16; ++c) {
                cm += (unsigned)__popcll(__ballot(fkey(v[c].x) > mid));
                cm += (unsigned)__popcll(__ballot(fkey(v[c].y) > mid));
                cm += (unsigned)__popcll(__ballot(fkey(v[c].z) > mid));
                cm += (unsigned)__popcll(__ballot(fkey(v[c].w) > mid));
            }
            if (cm >= K_SEL) { lo = mid; c_lo = cm; }
            else             { hi = mid; c_hi = cm; }
        }
        thrf = finv(hi);
        gt = c_hi;
        eqc = c_lo - c_hi;
    }

    const unsigned int need = K_SEL - gt;     // >= 1 by search invariant
    float4* ov = (float4*)(out + base);

    if (eqc == need) {
        // common case: keep everything >= thr (exactly K survive)
        #pragma unroll
        for (int c = 0; c < 16; ++c) {
            float4 w = v[c];
            w.x = (w.x >= thrf) ? w.x : 0.0f;
            w.y = (w.y >= thrf) ? w.y : 0.0f;
            w.z = (w.z >= thrf) ? w.z : 0.0f;
            w.w = (w.w >= thrf) ? w.w : 0.0f;
            nt_store4(&ov[lane + 64 * c], w);
        }
    } else {
        // rare tie path: keep first `need` equals in global index order
        // element index = 256*c + 4*lane + j  -> order (c, lane, j)
        unsigned int base_c = 0;
        #pragma unroll
        for (int c = 0; c < 16; ++c) {
            unsigned long long m0 = __ballot(v[c].x == thrf);
            unsigned long long m1 = __ballot(v[c].y == thrf);
            unsigned long long m2 = __ballot(v[c].z == thrf);
            unsigned long long m3 = __ballot(v[c].w == thrf);
            unsigned int pl = prefcount(m0) + prefcount(m1)
                            + prefcount(m2) + prefcount(m3);
            unsigned int b0 = (unsigned)((m0 >> lane) & 1ull);
            unsigned int b1 = (unsigned)((m1 >> lane) & 1ull);
            unsigned int b2 = (unsigned)((m2 >> lane) & 1ull);
            unsigned int r0 = base_c + pl;
            unsigned int r1 = r0 + b0;
            unsigned int r2 = r1 + b1;
            unsigned int r3 = r2 + b2;
            float4 w = v[c];
            w.x = (w.x > thrf || (w.x == thrf && r0 < need)) ? w.x : 0.0f;
            w.y = (w.y > thrf || (w.y == thrf && r1 < need)) ? w.y : 0.0f;
            w.z = (w.z > thrf || (w.z == thrf && r2 < need)) ? w.z : 0.0f;
            w.w = (w.w > thrf || (w.w == thrf && r3 < need)) ? w.w : 0.0f;
            nt_store4(&ov[lane + 64 * c], w);
            base_c += (unsigned)__popcll(m0) + (unsigned)__popcll(m1)
                    + (unsigned)__popcll(m2) + (unsigned)__popcll(m3);
        }
    }
}

extern "C" void kernel_launch(void* const* d_in, const int* in_sizes, int n_in,
                              void* d_out, int out_size, void* d_ws, size_t ws_size,
                              hipStream_t stream) {
    const float* x = (const float*)d_in[0];
    float* out = (float*)d_out;
    int rows = in_sizes[0] / DIM;             // 16384
    sparsify_topk<<<rows / WPB, 256, 0, stream>>>(x, out);
}